// Round 5
// baseline (21.654 us; speedup 1.0000x reference)
//
#include <hip/hip_runtime.h>
#include <hip/hip_bf16.h>

// Problem constants (from reference setup_inputs): emission [B, T, V] float32
#define CTC_B 64
#define CTC_T 8192
#define CTC_V 32
#define BLANK 0

typedef float f32x4 __attribute__((ext_vector_type(4)));

// ---------------------------------------------------------------------------
// Kernel 1: argmax over labels. A group of 4 lanes owns TWO rows (2g, 2g+1);
// each lane issues 4 independent non-temporal float4 loads (full 64B-line
// coalescing: 16 lines per load instruction, 4 instructions cover 4 KB
// contiguous). 16 384 waves (half of R4) -> per-wave overhead halves.
// First-occurrence tie-break: in-lane indices ascending with strict '>',
// cross-lane reduce prefers the smaller index on exact float equality.
// ---------------------------------------------------------------------------
__global__ __launch_bounds__(256) void ctc_argmax_kernel(
    const float* __restrict__ em, unsigned char* __restrict__ idx) {
    const int tid = blockIdx.x * blockDim.x + threadIdx.x;
    const int g   = tid >> 2;        // group -> rows 2g, 2g+1
    const int sub = tid & 3;

    const f32x4* base = reinterpret_cast<const f32x4*>(em);
    const f32x4* pa = base + ((size_t)(2 * g)    ) * 8 + sub;
    const f32x4* pb = base + ((size_t)(2 * g) + 1) * 8 + sub;
    f32x4 a0 = __builtin_nontemporal_load(pa);      // rowA elems 4s..4s+3
    f32x4 a1 = __builtin_nontemporal_load(pa + 4);  // rowA elems 16+4s..
    f32x4 b0 = __builtin_nontemporal_load(pb);      // rowB elems 4s..4s+3
    f32x4 b1 = __builtin_nontemporal_load(pb + 4);  // rowB elems 16+4s..

    const int i1 = sub * 4, i2 = 16 + sub * 4;

    float bA = a0.x; int iA = i1;
    if (a0.y > bA) { bA = a0.y; iA = i1 + 1; }
    if (a0.z > bA) { bA = a0.z; iA = i1 + 2; }
    if (a0.w > bA) { bA = a0.w; iA = i1 + 3; }
    if (a1.x > bA) { bA = a1.x; iA = i2;     }
    if (a1.y > bA) { bA = a1.y; iA = i2 + 1; }
    if (a1.z > bA) { bA = a1.z; iA = i2 + 2; }
    if (a1.w > bA) { bA = a1.w; iA = i2 + 3; }

    float bB = b0.x; int iB = i1;
    if (b0.y > bB) { bB = b0.y; iB = i1 + 1; }
    if (b0.z > bB) { bB = b0.z; iB = i1 + 2; }
    if (b0.w > bB) { bB = b0.w; iB = i1 + 3; }
    if (b1.x > bB) { bB = b1.x; iB = i2;     }
    if (b1.y > bB) { bB = b1.y; iB = i2 + 1; }
    if (b1.z > bB) { bB = b1.z; iB = i2 + 2; }
    if (b1.w > bB) { bB = b1.w; iB = i2 + 3; }

    // reduce across the 4-lane group (xor masks 1,2 stay in-group)
#pragma unroll
    for (int m = 1; m < 4; m <<= 1) {
        float oA = __shfl_xor(bA, m, 64);
        int   jA = __shfl_xor(iA, m, 64);
        float oB = __shfl_xor(bB, m, 64);
        int   jB = __shfl_xor(iB, m, 64);
        if (oA > bA || (oA == bA && jA < iA)) { bA = oA; iA = jA; }
        if (oB > bB || (oB == bB && jB < iB)) { bB = oB; iB = jB; }
    }
    if (sub == 0) {   // rows 2g,2g+1 adjacent -> one aligned 2-byte store
        unsigned short pk = (unsigned short)((iA & 0xff) | ((iB & 0xff) << 8));
        *reinterpret_cast<unsigned short*>(idx + 2 * g) = pk;
    }
}

// ---------------------------------------------------------------------------
// SWAR: high bit of each byte set iff that byte of x is nonzero.
// ---------------------------------------------------------------------------
__device__ __forceinline__ unsigned long long nzmask(unsigned long long x) {
    return (x | ((x & 0x7f7f7f7f7f7f7f7fULL) + 0x7f7f7f7f7f7f7f7fULL))
           & 0x8080808080808080ULL;
}

// ---------------------------------------------------------------------------
// Kernel 2 (fused colkeep + compact): one block of 1024 threads per batch
// row; each thread owns 8 CONSECUTIVE columns (one u64 byte-vector). Single
// pass, single barrier:
//   colkeep: SWAR compare of column t vs t-1 for batch rows 0,1 branchless,
//            rare loop over rows 2..63 only while some byte is undecided.
//   scan:    per-thread popcount -> wave shfl_up scan -> 16-int LDS -> barrier
//   scatter: <=8 consecutive int stores per thread + vectorized tail fill.
// ---------------------------------------------------------------------------
__global__ __launch_bounds__(1024) void ctc_compact_kernel(
    const unsigned char* __restrict__ idx,
    int* __restrict__ btokens, int* __restrict__ lens) {
    const int b   = blockIdx.x;
    const int tid = threadIdx.x;
    const int t8  = tid * 8;                     // first column this thread owns
    const unsigned char* row = idx + (size_t)b * CTC_T;
    int* orow = btokens + (size_t)b * CTC_T;

    __shared__ int s_wsum[16];
    const int lane = tid & 63;
    const int wid  = tid >> 6;

    // --- load own 8 values + boundary byte, and dedup rows 0,1 ---
    const unsigned long long xv = *reinterpret_cast<const unsigned long long*>(row + t8);
    const unsigned char* r0 = idx;               // batch row 0
    const unsigned char* r1 = idx + CTC_T;       // batch row 1
    unsigned long long x0 = *reinterpret_cast<const unsigned long long*>(r0 + t8);
    unsigned long long x1 = *reinterpret_cast<const unsigned long long*>(r1 + t8);
    unsigned char p0 = (t8 == 0) ? (unsigned char)0 : r0[t8 - 1];
    unsigned char p1 = (t8 == 0) ? (unsigned char)0 : r1[t8 - 1];

    // colkeep high-bit mask: byte j <-> column t8+j ; prev column = byte j-1
    unsigned long long hk = nzmask(x0 ^ ((x0 << 8) | (unsigned long long)p0))
                          | nzmask(x1 ^ ((x1 << 8) | (unsigned long long)p1));
    if (t8 == 0) hk |= 0x80ULL;                  // col_keep[0] = 1 always

    unsigned long long und = ~hk & 0x8080808080808080ULL;
    for (int bb = 2; bb < CTC_B && und; ++bb) {
        const unsigned char* rb = idx + (size_t)bb * CTC_T;
        unsigned long long xb = *reinterpret_cast<const unsigned long long*>(rb + t8);
        unsigned char pb = (t8 == 0) ? (unsigned char)0 : rb[t8 - 1];
        hk |= nzmask(xb ^ ((xb << 8) | (unsigned long long)pb));
        und = ~hk & 0x8080808080808080ULL;
    }

    // keep = col_keep & (value != BLANK)   (BLANK==0 -> nonzero byte)
    const unsigned long long keep_hi = hk & nzmask(xv);
    const int c = __popcll(keep_hi);

    // --- block exclusive scan of per-thread counts ---
    int scan = c;
#pragma unroll
    for (int m = 1; m < 64; m <<= 1) {
        int o = __shfl_up(scan, m, 64);
        if (lane >= m) scan += o;
    }
    if (lane == 63) s_wsum[wid] = scan;          // wave total (inclusive of last)
    __syncthreads();

    int woff = 0, total = 0;
#pragma unroll
    for (int w = 0; w < 16; ++w) {
        int x = s_wsum[w];
        if (w < wid) woff += x;
        total += x;
    }
    int pos = woff + (scan - c);                 // global exclusive prefix

    // --- scatter kept tokens (consecutive per thread) ---
#pragma unroll
    for (int j = 0; j < 8; ++j) {
        if (keep_hi & (0x80ULL << (8 * j))) {
            orow[pos++] = (int)((xv >> (8 * j)) & 0xffULL);
        }
    }

    // --- tail zero-fill (int4-vectorized) + lens ---
    int vstart = (total + 3) & ~3;               // 16B-aligned fill start
    if (tid < vstart - total) orow[total + tid] = BLANK;
    int4* vout = reinterpret_cast<int4*>(orow + vstart);
    const int nvec = (CTC_T - vstart) >> 2;
    const int4 z = make_int4(BLANK, BLANK, BLANK, BLANK);
    for (int i = tid; i < nvec; i += 1024) vout[i] = z;
    if (tid == 0) lens[b] = total;
}

// ---------------------------------------------------------------------------
extern "C" void kernel_launch(void* const* d_in, const int* in_sizes, int n_in,
                              void* d_out, int out_size, void* d_ws, size_t ws_size,
                              hipStream_t stream) {
    const float* emission = (const float*)d_in[0];
    int* out = (int*)d_out;                 // [B*T btokens][B lens], int32
    int* btokens = out;
    int* lens = out + (size_t)CTC_B * CTC_T;

    unsigned char* idx = (unsigned char*)d_ws;   // B*T bytes

    // 4 lanes per row, 2 rows per 4-lane group -> B*T*2 threads
    const int total_threads = CTC_B * CTC_T * 2;
    ctc_argmax_kernel<<<total_threads / 256, 256, 0, stream>>>(emission, idx);
    ctc_compact_kernel<<<CTC_B, 1024, 0, stream>>>(idx, btokens, lens);
}